// Round 5
// baseline (290.280 us; speedup 1.0000x reference)
//
#include <hip/hip_runtime.h>
#include <hip/hip_bf16.h>
#include <stdint.h>

// ---------- types ----------
typedef __bf16 v8bf __attribute__((ext_vector_type(8)));
typedef float  v4f  __attribute__((ext_vector_type(4)));

__device__ __forceinline__ ushort f2bf(float f) {
    union { float f; uint32_t u; } x; x.f = f;
    uint32_t r = (x.u + 0x7FFFu + ((x.u >> 16) & 1u)) >> 16;
    return (ushort)r;
}
// pack two non-negative floats to bf16x2 (round-half-up): 2 add + 1 v_perm
__device__ __forceinline__ uint32_t pack2bf(float a, float b) {
    union { float f; uint32_t u; } xa, xb; xa.f = a; xb.f = b;
    return __builtin_amdgcn_perm(xb.u + 0x8000u, xa.u + 0x8000u, 0x07060302u);
}

__device__ __forceinline__ void load_lds16(const void* g, void* l) {
    __builtin_amdgcn_global_load_lds(
        (const __attribute__((address_space(1))) uint32_t*)g,
        (__attribute__((address_space(3))) uint32_t*)l, 16, 0, 0);
}

// phase barrier: raw s_barrier (NO implicit vmcnt(0) drain, unlike __syncthreads)
// fenced with sched_barrier so the compiler cannot move ds/MFMA across phases.
__device__ __forceinline__ void pbar() {
    __builtin_amdgcn_sched_barrier(0);
    __builtin_amdgcn_s_barrier();
    __builtin_amdgcn_sched_barrier(0);
}
template <int N>
__device__ __forceinline__ void vmwait() {
    if constexpr (N == 0)      asm volatile("s_waitcnt vmcnt(0)" ::: "memory");
    else if constexpr (N == 3) asm volatile("s_waitcnt vmcnt(3)" ::: "memory");
    else                       asm volatile("s_waitcnt vmcnt(4)" ::: "memory");
    __builtin_amdgcn_sched_barrier(0);
}

// ---------- elementwise convert ----------
__global__ void cvt_f32_bf16_k(const float4* __restrict__ src,
                               ushort* __restrict__ dst, int n4) {
    int i = blockIdx.x * 256 + threadIdx.x;
    if (i >= n4) return;
    float4 f = src[i];
    ushort4 u = make_ushort4(f2bf(f.x), f2bf(f.y), f2bf(f.z), f2bf(f.w));
    *(ushort4*)(dst + 4 * (size_t)i) = u;
}

// ---------- fused LDS-tiled transpose+convert for all 4 weights ----------
__global__ __launch_bounds__(256) void transpose_all(
    const float* __restrict__ Wq, const float* __restrict__ Wk,
    const float* __restrict__ Wv, const float* __restrict__ Wo,
    ushort* __restrict__ wqk_t, ushort* __restrict__ wv_t,
    ushort* __restrict__ wo_t) {
    __shared__ ushort tile[64][65];
    const int tid = threadIdx.x;
    const int ix = blockIdx.x, k0 = blockIdx.y * 64;
    const float* src; ushort* dst; int N, n0;
    if (ix < 32)      { src = Wq; dst = wqk_t;                       N = 2048; n0 = ix * 64; }
    else if (ix < 40) { src = Wk; dst = wqk_t + (size_t)2048 * 2048; N = 512;  n0 = (ix - 32) * 64; }
    else if (ix < 48) { src = Wv; dst = wv_t;                        N = 512;  n0 = (ix - 40) * 64; }
    else              { src = Wo; dst = wo_t;                        N = 2048; n0 = (ix - 48) * 64; }
    const int nn = tid & 63, kb = tid >> 6;
#pragma unroll
    for (int p = 0; p < 16; ++p) {
        int kk = p * 4 + kb;
        tile[kk][nn] = f2bf(src[(size_t)(k0 + kk) * N + n0 + nn]);
    }
    __syncthreads();
    const int nr = tid >> 2, kch = (tid & 3) * 16;
    union { ushort u[16]; uint4 q[2]; } tmp;
#pragma unroll
    for (int j = 0; j < 16; ++j) tmp.u[j] = tile[kch + j][nr];
    uint4* out = (uint4*)&dst[(size_t)(n0 + nr) * 2048 + k0 + kch];
    out[0] = tmp.q[0];
    out[1] = tmp.q[1];
}

// ---------- 256-row-tile 8-phase GEMM (T2+T3+T4+T5), K = 2048 ----------
// BM=256, BK=64, 8 waves (2M x 4N), 512 threads. BN = 256 (qkv) or 128 (out).
// LDS: A 2buf x 2kh x [256][32] (64 KB) + B 2buf x 2kh x [BN][32].
// Staging: global_load_lds, K-half granularity, 1 half-tile per phase, source
// chunk pre-swizzled (chunk ^= row&3) + swizzled ds_read chunk; LDS dest linear.
// Counted vmcnt (never 0 in steady state): allowed in-flight = A-kh(2) + B-kh(BISS).
template <int BN, bool OUT_BF16>
__device__ __forceinline__ void gemm256_body(
    const ushort* __restrict__ A, const ushort* __restrict__ Bt,
    void* __restrict__ Cout, int ldc, int m0, int n0,
    ushort* As, ushort* Bs) {
    constexpr int K    = 2048;
    constexpr int NKT  = K / 64;        // 32 K-tiles
    constexpr int NTN  = BN / 64;       // B n-frags per wave (4 or 2)
    constexpr int BEL  = BN * 32;       // elements per B kh-region
    constexpr int BISS = NTN / 2;       // G-load issues per B kh stage (2 or 1)
    constexpr int VMK  = 2 + BISS;      // counted-vmcnt allowance

    const int tid  = threadIdx.x;
    const int wv   = tid >> 6, lane = tid & 63;
    const int wr   = wv >> 2,  wc   = wv & 3;
    const int mq   = lane & 15, quad = lane >> 4;
    const int cho  = ((quad ^ (mq & 3)) << 3);   // swizzled read-chunk (elements)

    // staging source pointers (pre-swizzled global chunk; rule #21 both-sides)
    const int srow = tid >> 2;
    const int cxr  = (((tid & 3) ^ (srow & 3)) << 3);
    const ushort* sA0 = A  + (size_t)(m0 + srow) * K + cxr;
    const ushort* sA1 = sA0 + (size_t)128 * K;
    const ushort* sB0 = Bt + (size_t)(n0 + srow) * K + cxr;
    const ushort* sB1 = sB0 + (size_t)128 * K;   // unused when BN==128
    const int sdo = wv * 512;                    // wave-uniform LDS dest offset

    const int arow = wr * 128 + mq;
    const int brow = wc * (NTN * 16) + mq;

    v4f acc[8][NTN] = {};

    auto stageA = [&](int buf, int kh, int kt) {
        const int ko = kt * 64 + kh * 32;
        ushort* d = As + (buf * 2 + kh) * 8192 + sdo;
        load_lds16(sA0 + ko, d);
        load_lds16(sA1 + ko, d + 4096);
    };
    auto stageB = [&](int buf, int kh, int kt) {
        const int ko = kt * 64 + kh * 32;
        ushort* d = Bs + (buf * 2 + kh) * BEL + sdo;
        load_lds16(sB0 + ko, d);
        if constexpr (BISS == 2) load_lds16(sB1 + ko, d + 4096);
    };
    auto rdA = [&](v8bf (&r)[4], const ushort* kb, int r0) {
#pragma unroll
        for (int i = 0; i < 4; ++i)
            r[i] = *(const v8bf*)&kb[(r0 + i * 16) * 32 + cho];
    };
    auto rdB = [&](v8bf (&r)[NTN], const ushort* kb) {
#pragma unroll
        for (int i = 0; i < NTN; ++i)
            r[i] = *(const v8bf*)&kb[(brow + i * 16) * 32 + cho];
    };
    auto mma = [&](int mtb, const v8bf (&a)[4], const v8bf (&b)[NTN]) {
#pragma unroll
        for (int i = 0; i < 4; ++i)
#pragma unroll
            for (int nt = 0; nt < NTN; ++nt)
                acc[mtb + i][nt] = __builtin_amdgcn_mfma_f32_16x16x32_bf16(
                    a[i], b[nt], acc[mtb + i][nt], 0, 0, 0);
    };

    // prologue: tile 0 into buf 0 (order A0,B0,A1,B1); wait oldest 2 half-tiles
    stageA(0, 0, 0); stageB(0, 0, 0); stageA(0, 1, 0); stageB(0, 1, 0);
    vmwait<VMK>();
    __builtin_amdgcn_s_barrier();
    __builtin_amdgcn_sched_barrier(0);

#pragma unroll 1
    for (int t = 0; t < NKT; ++t) {
        const int p = t & 1, pn = p ^ 1;
        const bool more = (t + 1 < NKT);
        const ushort* a0 = As + p * 16384;
        const ushort* a1 = a0 + 8192;
        const ushort* b0 = Bs + p * (2 * BEL);
        const ushort* b1 = b0 + BEL;
        v8bf af[4], bfr[NTN];

        // phase 1: read ks0 (A mt0-3 + B all nt); stage A-kh0(t+1); MFMA
        rdA(af, a0, arow); rdB(bfr, b0);
        if (more) stageA(pn, 0, t + 1);
        pbar();
        __builtin_amdgcn_s_setprio(1); mma(0, af, bfr); __builtin_amdgcn_s_setprio(0);
        pbar();
        // phase 2: read ks0 A mt4-7; stage B-kh0(t+1); MFMA; vmcnt -> kh1 visible
        rdA(af, a0, arow + 64);
        if (more) stageB(pn, 0, t + 1);
        pbar();
        __builtin_amdgcn_s_setprio(1); mma(4, af, bfr); __builtin_amdgcn_s_setprio(0);
        if (more) vmwait<VMK>(); else vmwait<0>();
        pbar();
        // phase 3: read ks1 (A mt0-3 + B all nt); stage A-kh1(t+1); MFMA
        rdA(af, a1, arow); rdB(bfr, b1);
        if (more) stageA(pn, 1, t + 1);
        pbar();
        __builtin_amdgcn_s_setprio(1); mma(0, af, bfr); __builtin_amdgcn_s_setprio(0);
        pbar();
        // phase 4: read ks1 A mt4-7; stage B-kh1(t+1); MFMA; vmcnt -> next kh0 visible
        rdA(af, a1, arow + 64);
        if (more) stageB(pn, 1, t + 1);
        pbar();
        __builtin_amdgcn_s_setprio(1); mma(4, af, bfr); __builtin_amdgcn_s_setprio(0);
        if (more) vmwait<VMK>();
        pbar();
    }

    // epilogue: C-layout row = quad*4+reg, col = mq
#pragma unroll
    for (int mt = 0; mt < 8; ++mt) {
        const int r = m0 + wr * 128 + mt * 16 + quad * 4;
#pragma unroll
        for (int nt = 0; nt < NTN; ++nt) {
            const int c = n0 + wc * (NTN * 16) + nt * 16 + mq;
#pragma unroll
            for (int reg = 0; reg < 4; ++reg) {
                if (OUT_BF16)
                    ((ushort*)Cout)[(size_t)(r + reg) * ldc + c] = f2bf(acc[mt][nt][reg]);
                else
                    ((float*)Cout)[(size_t)(r + reg) * ldc + c] = acc[mt][nt][reg];
            }
        }
    }
}

// fused QK-projection (160 blocks) + V^T-projection (32 blocks); 1 block/CU
__global__ __launch_bounds__(512, 2) void gemm_qkv(
    const ushort* __restrict__ xb, const ushort* __restrict__ wqk_t,
    const ushort* __restrict__ wv_t, ushort* __restrict__ qkb,
    ushort* __restrict__ vtb) {
    __shared__ __align__(16) ushort As[32768];   // 64 KB
    __shared__ __align__(16) ushort Bs[32768];   // 64 KB
    int w = (blockIdx.x & 7) * 24 + (blockIdx.x >> 3);   // XCD-chunked (192 = 8*24)
    const ushort *Ap, *Bp; ushort* Cp; int ldc, m0, n0;
    if (w < 160) {   // qkb[4096][2560] = xb * wqk_t^T
        Ap = xb; Bp = wqk_t; Cp = qkb; ldc = 2560;
        m0 = (w / 10) * 256; n0 = (w % 10) * 256;
    } else {         // vtb[512][4096] = wv_t * xb^T
        w -= 160;
        Ap = wv_t; Bp = xb; Cp = vtb; ldc = 4096;
        m0 = (w >> 4) * 256; n0 = (w & 15) * 256;
    }
    gemm256_body<256, true>(Ap, Bp, Cp, ldc, m0, n0, As, Bs);
}

// output projection: d_out[4096][2048] f32 = attn_out * wo_t^T
// BN=128 -> 256 blocks = exactly 1/CU (BN=256 would idle half the machine)
__global__ __launch_bounds__(512, 2) void gemm_out(
    const ushort* __restrict__ A, const ushort* __restrict__ Bt,
    float* __restrict__ C) {
    __shared__ __align__(16) ushort As[32768];   // 64 KB
    __shared__ __align__(16) ushort Bs[16384];   // 32 KB
    const int w = (blockIdx.x & 7) * 32 + (blockIdx.x >> 3);   // 256 = 8*32
    gemm256_body<128, false>(A, Bt, C, 2048, (w >> 4) * 256, (w & 15) * 128, As, Bs);
}

// ---------- flash attention v10 (unchanged; balanced per-CU qt assignment) ----------
constexpr float SC2 = 0.18033688011f;   // 0.125 * log2(e)
constexpr float MB2 = 14.4269504089f;   // 10 * log2(e)  (fixed softmax max M=10, exact)

template <bool MASK>
__device__ __forceinline__ void attn_compute(
    int kv0, int qrow, int mq, int quad, int lane_lo,
    const ushort* Ks, const ushort* Vs, const v8bf ones,
    const v8bf (&qf)[2][2], v4f (&oacc)[2][4], v4f (&osum)[2]) {
    const bool hi = quad >= 2;
    const int swz = mq & 7;
#pragma unroll
    for (int half = 0; half < 2; ++half) {
        uint32_t pk[2][2][2];
#pragma unroll
        for (int ntl = 0; ntl < 2; ++ntl) {
            const int nt = 2 * half + ntl;
            v4f sacc[2] = {{0.f,0.f,0.f,0.f}, {0.f,0.f,0.f,0.f}};
#pragma unroll
            for (int ks = 0; ks < 2; ++ks) {
                v8bf kb = *(const v8bf*)&Ks[(nt * 16 + mq) * 64 + (((ks << 2) + quad) ^ swz) * 8];
                sacc[0] = __builtin_amdgcn_mfma_f32_16x16x32_bf16(kb, qf[0][ks], sacc[0], 0, 0, 0);
                sacc[1] = __builtin_amdgcn_mfma_f32_16x16x32_bf16(kb, qf[1][ks], sacc[1], 0, 0, 0);
            }
#pragma unroll
            for (int g = 0; g < 2; ++g) {
                float pr[4];
#pragma unroll
                for (int reg = 0; reg < 4; ++reg) {
                    float s = sacc[g][reg];
                    if (MASK) {
                        const int kv = kv0 + nt * 16 + quad * 4 + reg;
                        const int q  = qrow + 16 * g + mq;
                        if (kv > q) s = -3.0e38f;
                    }
                    pr[reg] = __builtin_amdgcn_exp2f(fmaf(s, SC2, -MB2));
                }
                pk[g][ntl][0] = pack2bf(pr[0], pr[1]);
                pk[g][ntl][1] = pack2bf(pr[2], pr[3]);
            }
        }
        v8bf pf[2];
#pragma unroll
        for (int g = 0; g < 2; ++g) {
            uint32_t a0 = __shfl(pk[g][0][0], lane_lo);
            uint32_t b0 = __shfl(pk[g][1][0], lane_lo);
            uint32_t a1 = __shfl(pk[g][0][1], lane_lo);
            uint32_t b1 = __shfl(pk[g][1][1], lane_lo);
            uint32_t a2 = __shfl(pk[g][0][0], lane_lo + 16);
            uint32_t b2 = __shfl(pk[g][1][0], lane_lo + 16);
            uint32_t a3 = __shfl(pk[g][0][1], lane_lo + 16);
            uint32_t b3 = __shfl(pk[g][1][1], lane_lo + 16);
            union { uint32_t d[4]; v8bf v; } u;
            u.d[0] = hi ? b0 : a0;
            u.d[1] = hi ? b1 : a1;
            u.d[2] = hi ? b2 : a2;
            u.d[3] = hi ? b3 : a3;
            pf[g] = u.v;
            osum[g] = __builtin_amdgcn_mfma_f32_16x16x32_bf16(pf[g], ones, osum[g], 0, 0, 0);
        }
#pragma unroll
        for (int hdt = 0; hdt < 4; ++hdt) {
            v8bf vb = *(const v8bf*)&Vs[(hdt * 16 + mq) * 64 + (((half << 2) + quad) ^ swz) * 8];
            oacc[0][hdt] = __builtin_amdgcn_mfma_f32_16x16x32_bf16(pf[0], vb, oacc[0][hdt], 0, 0, 0);
            oacc[1][hdt] = __builtin_amdgcn_mfma_f32_16x16x32_bf16(pf[1], vb, oacc[1][hdt], 0, 0, 0);
        }
    }
}

__global__ __launch_bounds__(256, 4) void attn_fwd(
    const ushort* __restrict__ qkb, const ushort* __restrict__ vt,
    ushort* __restrict__ outp) {
    __shared__ __align__(16) ushort Ks[2][4096];
    __shared__ __align__(16) ushort Vs[2][4096];

    const int tid  = threadIdx.x;
    const int wv   = tid >> 6, lane = tid & 63;
    const int mq = lane & 15, quad = lane >> 4;
    const int lane_lo = (quad & 1) * 32 + mq;

    // balanced work assignment: same-CU blocks {i, i+256, i+512, i+768} get
    // qt sets {2j, 2j+1, 15-2j, 14-2j} -> per-CU tile total = 68, constant.
    const int i = blockIdx.x;
    const int u = i & 255, s = i >> 8;
    const int h = u & 31, j = u >> 5;
    const int b = s >> 1;
    const int qt = (s == 0) ? 2 * j
                 : (s == 1) ? 2 * j + 1
                 : (s == 2) ? 15 - 2 * j
                            : 14 - 2 * j;
    const int g = h >> 2;
    const int qb0  = qt * 128;
    const int qrow = qb0 + wv * 32;

    union { ushort u[8]; v8bf v; } one_u;
#pragma unroll
    for (int ii = 0; ii < 8; ++ii) one_u.u[ii] = 0x3F80;
    const v8bf ones = one_u.v;

    v8bf qf[2][2];
#pragma unroll
    for (int gg = 0; gg < 2; ++gg) {
        const ushort* qp = qkb + (size_t)(b * 2048 + qrow + 16 * gg + mq) * 2560 + h * 64 + quad * 8;
        qf[gg][0] = *(const v8bf*)qp;
        qf[gg][1] = *(const v8bf*)(qp + 32);
    }

    v4f oacc[2][4] = {};
    v4f osum[2] = {};

    const ushort* kg = qkb + (size_t)(b * 2048) * 2560 + 2048 + g * 64;
    const ushort* vg = vt + (size_t)(g * 64) * 4096 + b * 2048;

    const int sr = lane >> 3;
    const int gc = (lane & 7) ^ sr;
    const ushort* kb0 = kg + (size_t)(wv * 16 + sr) * 2560 + gc * 8;
    const ushort* kb1 = kb0 + (size_t)8 * 2560;
    const ushort* vb0 = vg + (size_t)(wv * 16 + sr) * 4096 + gc * 8;
    const ushort* vb1 = vb0 + (size_t)8 * 4096;
    const int ldso = wv * 1024;

    const int ntiles = 2 * qt + 2;

    load_lds16(kb0, &Ks[0][ldso]);
    load_lds16(kb1, &Ks[0][ldso + 512]);
    load_lds16(vb0, &Vs[0][ldso]);
    load_lds16(vb1, &Vs[0][ldso + 512]);
    __syncthreads();

#pragma unroll 1
    for (int jt = 0; jt < ntiles; ++jt) {
        const int kv0 = jt * 64;
        const int p = jt & 1;
        if (jt + 1 < ntiles) {
            const int nk = kv0 + 64;
            load_lds16(kb0 + (size_t)nk * 2560, &Ks[p ^ 1][ldso]);
            load_lds16(kb1 + (size_t)nk * 2560, &Ks[p ^ 1][ldso + 512]);
            load_lds16(vb0 + nk, &Vs[p ^ 1][ldso]);
            load_lds16(vb1 + nk, &Vs[p ^ 1][ldso + 512]);
        }
        if (kv0 <= qrow) {
            if (kv0 + 64 > qrow)
                attn_compute<true>(kv0, qrow, mq, quad, lane_lo, Ks[p], Vs[p], ones, qf, oacc, osum);
            else
                attn_compute<false>(kv0, qrow, mq, quad, lane_lo, Ks[p], Vs[p], ones, qf, oacc, osum);
        }
        __syncthreads();
    }

#pragma unroll
    for (int gg = 0; gg < 2; ++gg) {
#pragma unroll
        for (int reg = 0; reg < 4; ++reg) {
            const float invr = 1.0f / osum[gg][reg];
            const int rr = qrow + 16 * gg + quad * 4 + reg;
#pragma unroll
            for (int hdt = 0; hdt < 4; ++hdt)
                outp[(size_t)(b * 2048 + rr) * 2048 + h * 64 + hdt * 16 + mq] =
                    f2bf(oacc[gg][hdt][reg] * invr);
        }
    }
}

// ---------- launch ----------
extern "C" void kernel_launch(void* const* d_in, const int* in_sizes, int n_in,
                              void* d_out, int out_size, void* d_ws, size_t ws_size,
                              hipStream_t stream) {
    const float* x  = (const float*)d_in[0];
    const float* Wq = (const float*)d_in[1];
    const float* Wk = (const float*)d_in[2];
    const float* Wv = (const float*)d_in[3];
    const float* Wo = (const float*)d_in[4];

    char* ws = (char*)d_ws;
    ushort* xb    = (ushort*)(ws);                  // [4096][2048] x bf16; later attn output
    ushort* wqk_t = (ushort*)(ws + 16777216);       // [2560][2048]
    ushort* wv_t  = (ushort*)(ws + 27262976);       // [512][2048]
    ushort* wo_t  = (ushort*)(ws + 29360128);       // [2048][2048]
    ushort* qkb   = (ushort*)(ws + 37748736);       // [4096][2560]  Q|K
    ushort* vtb   = (ushort*)(ws + 58720256);       // [512][4096]   V^T

    cvt_f32_bf16_k<<<8192, 256, 0, stream>>>((const float4*)x, xb, 2097152);
    transpose_all<<<dim3(80, 32), 256, 0, stream>>>(Wq, Wk, Wv, Wo, wqk_t, wv_t, wo_t);

    gemm_qkv<<<192, 512, 0, stream>>>(xb, wqk_t, wv_t, qkb, vtb);
    attn_fwd<<<1024, 256, 0, stream>>>(qkb, vtb, xb);
    gemm_out<<<256, 512, 0, stream>>>(xb, wo_t, (float*)d_out);
}